// Round 1
// baseline (648.353 us; speedup 1.0000x reference)
//
#include <hip/hip_runtime.h>
#include <hip/hip_bf16.h>

#define HIDDEN 2048
#define NH 16
#define HD 128
#define BATCH 2
#define SEQ 2048

typedef __attribute__((ext_vector_type(8))) short short8;
typedef __attribute__((ext_vector_type(4))) float floatx4;

__device__ inline unsigned short f2bf(float f) {
  union { float f; unsigned int u; } x; x.f = f;
  unsigned int r = x.u + 0x7fffu + ((x.u >> 16) & 1u);
  return (unsigned short)(r >> 16);
}

__device__ inline void async_cp16(const void* g, void* l) {
  __builtin_amdgcn_global_load_lds(
      (const __attribute__((address_space(1))) unsigned int*)g,
      (__attribute__((address_space(3))) unsigned int*)l, 16, 0, 0);
}

// ---------------- f32 -> bf16 convert ----------------
__global__ __launch_bounds__(256) void cvt_kernel(const float* __restrict__ in,
                                                  unsigned short* __restrict__ out,
                                                  int n) {
  int i = (blockIdx.x * 256 + threadIdx.x) * 4;
  if (i + 3 < n) {
    float4 v = *reinterpret_cast<const float4*>(in + i);
    ushort4 o;
    o.x = f2bf(v.x); o.y = f2bf(v.y); o.z = f2bf(v.z); o.w = f2bf(v.w);
    *reinterpret_cast<ushort4*>(out + i) = o;
  }
}

// ---------------- NT GEMM ----------------
template<int MODE>
__global__ __launch_bounds__(256, 2) void gemm_nt(const unsigned short* __restrict__ A,
                                                  const unsigned short* __restrict__ Bw,
                                                  const float* __restrict__ bias,
                                                  float* __restrict__ outF,
                                                  unsigned short* __restrict__ outQ) {
  __shared__ __align__(16) unsigned short As[4][128][8];
  __shared__ __align__(16) unsigned short Bs[4][128][8];
  const int t = threadIdx.x;
  const int lane = t & 63;
  const int w = t >> 6;
  const int wr = w >> 1, wc = w & 1;
  const int row0 = blockIdx.x * 128;
  const int col0 = blockIdx.y * 128;

  floatx4 acc[4][4] = {};

  for (int kt = 0; kt < 2048 / 32; ++kt) {
    __syncthreads();
    const int kb = kt * 32;
#pragma unroll
    for (int cc = 0; cc < 2; ++cc) {
      int c = t + cc * 256;
      int k8 = c >> 7;
      int r = c & 127;
      async_cp16(A + (size_t)(row0 + r) * 2048 + kb + k8 * 8, &As[0][0][0] + c * 8);
      async_cp16(Bw + (size_t)(col0 + r) * 2048 + kb + k8 * 8, &Bs[0][0][0] + c * 8);
    }
    __syncthreads();

    short8 af[4], bf[4];
#pragma unroll
    for (int m = 0; m < 4; ++m)
      af[m] = *(const short8*)&As[lane >> 4][wr * 64 + m * 16 + (lane & 15)][0];
#pragma unroll
    for (int n = 0; n < 4; ++n)
      bf[n] = *(const short8*)&Bs[lane >> 4][wc * 64 + n * 16 + (lane & 15)][0];
#pragma unroll
    for (int m = 0; m < 4; ++m)
#pragma unroll
      for (int n = 0; n < 4; ++n)
        acc[m][n] = __builtin_amdgcn_mfma_f32_16x16x32_bf16(af[m], bf[n], acc[m][n], 0, 0, 0);
  }

#pragma unroll
  for (int m = 0; m < 4; ++m) {
#pragma unroll
    for (int n = 0; n < 4; ++n) {
      int gcol = col0 + wc * 64 + n * 16 + (lane & 15);
      float bv = bias[gcol];
#pragma unroll
      for (int r = 0; r < 4; ++r) {
        int grow = row0 + wr * 64 + m * 16 + (lane >> 4) * 4 + r;
        float v = acc[m][n][r] + bv;
        if (MODE == 1) {
          outF[(size_t)grow * 2048 + gcol] = v;
        } else {
          int bb = grow >> 11;
          int ss = grow & 2047;
          int hh = gcol >> 7;
          int dd = gcol & 127;
          outQ[(((size_t)bb * NH + hh) * SEQ + ss) * HD + dd] = f2bf(v);
        }
      }
    }
  }
}

// ---------------- causal flash attention ----------------
__global__ __launch_bounds__(256, 2) void attn_kernel(const unsigned short* __restrict__ Q,
                                                      const unsigned short* __restrict__ Kg,
                                                      const unsigned short* __restrict__ Vg,
                                                      unsigned short* __restrict__ O) {
  __shared__ __align__(16) unsigned short Ks[16][32][8];
  __shared__ __align__(16) unsigned short VT[4096];
  __shared__ __align__(16) unsigned short Ps[4][512];

  const int t = threadIdx.x;
  const int lane = t & 63;
  const int w = t >> 6;
  const int bh = blockIdx.y;
  const int q0 = blockIdx.x * 64;
  const int bb = bh >> 4;
  const int hh = bh & 15;

  const unsigned short* Qb = Q + (size_t)bh * SEQ * HD;
  const unsigned short* Kb = Kg + (size_t)bh * SEQ * HD;
  const unsigned short* Vb = Vg + (size_t)bh * SEQ * HD;

  const int qw = q0 + w * 16;
  short8 aq[4];
#pragma unroll
  for (int kb = 0; kb < 4; ++kb)
    aq[kb] = *(const short8*)(Qb + (size_t)(qw + (lane & 15)) * HD + kb * 32 + (lane >> 4) * 8);

  floatx4 acc[8] = {};
  float mrun[4], lrun[4];
#pragma unroll
  for (int r = 0; r < 4; ++r) { mrun[r] = -1e30f; lrun[r] = 0.f; }

  const float scale = 0.08838834764831845f;
  const int ntiles = (q0 >> 5) + 2;

  for (int tk = 0; tk < ntiles; ++tk) {
    const int k0 = tk * 32;
    __syncthreads();
#pragma unroll
    for (int cc = 0; cc < 2; ++cc) {
      int c = t + cc * 256;
      async_cp16(Kb + (size_t)(k0 + (c & 31)) * HD + (c >> 5) * 8, &Ks[0][0][0] + c * 8);
    }
#pragma unroll
    for (int cc = 0; cc < 2; ++cc) {
      int c = t + cc * 256;
      int kv = c >> 4;
      int d0 = (c & 15) * 8;
      short8 vv = *(const short8*)(Vb + (size_t)(k0 + kv) * HD + d0);
#pragma unroll
      for (int j = 0; j < 8; ++j) {
        int dd = d0 + j;
        VT[((kv >> 3) * 1024) + ((dd ^ ((dd >> 3) & 7)) * 8) + (kv & 7)] = (unsigned short)vv[j];
      }
    }
    __syncthreads();

    float sv[2][4];
#pragma unroll
    for (int nb = 0; nb < 2; ++nb) {
      floatx4 s = {0.f, 0.f, 0.f, 0.f};
#pragma unroll
      for (int kb = 0; kb < 4; ++kb) {
        short8 bk = *(const short8*)&Ks[kb * 4 + (lane >> 4)][nb * 16 + (lane & 15)][0];
        s = __builtin_amdgcn_mfma_f32_16x16x32_bf16(aq[kb], bk, s, 0, 0, 0);
      }
#pragma unroll
      for (int r = 0; r < 4; ++r) sv[nb][r] = s[r] * scale;
    }
    if (k0 + 31 > q0) {
#pragma unroll
      for (int nb = 0; nb < 2; ++nb) {
        int kvg = k0 + nb * 16 + (lane & 15);
#pragma unroll
        for (int r = 0; r < 4; ++r) {
          int qg = qw + (lane >> 4) * 4 + r;
          if (kvg > qg) sv[nb][r] = -1e30f;
        }
      }
    }
#pragma unroll
    for (int r = 0; r < 4; ++r) {
      float mx = fmaxf(sv[0][r], sv[1][r]);
#pragma unroll
      for (int off = 8; off >= 1; off >>= 1)
        mx = fmaxf(mx, __shfl_xor(mx, off, 64));
      float mnew = fmaxf(mrun[r], mx);
      float p0 = __expf(sv[0][r] - mnew);
      float p1 = __expf(sv[1][r] - mnew);
      sv[0][r] = p0; sv[1][r] = p1;
      float rs = p0 + p1;
#pragma unroll
      for (int off = 8; off >= 1; off >>= 1)
        rs += __shfl_xor(rs, off, 64);
      float f = __expf(mrun[r] - mnew);
      lrun[r] = lrun[r] * f + rs;
      mrun[r] = mnew;
#pragma unroll
      for (int db = 0; db < 8; ++db) acc[db][r] *= f;
    }
    unsigned short* ps = &Ps[w][0];
#pragma unroll
    for (int nb = 0; nb < 2; ++nb)
#pragma unroll
      for (int r = 0; r < 4; ++r)
        ps[((nb * 2 + ((lane & 15) >> 3)) * 16 + (lane >> 4) * 4 + r) * 8 + (lane & 7)] =
            f2bf(sv[nb][r]);
    short8 pa = *(const short8*)(ps + (lane >> 4) * 128 + (lane & 15) * 8);
#pragma unroll
    for (int db = 0; db < 8; ++db) {
      int dg = db * 16 + (lane & 15);
      short8 bv = *(const short8*)&VT[((lane >> 4) * 1024) + ((dg ^ ((dg >> 3) & 7)) * 8)];
      acc[db] = __builtin_amdgcn_mfma_f32_16x16x32_bf16(pa, bv, acc[db], 0, 0, 0);
    }
  }

#pragma unroll
  for (int r = 0; r < 4; ++r) {
    float inv = 1.0f / lrun[r];
    int qg = qw + (lane >> 4) * 4 + r;
#pragma unroll
    for (int db = 0; db < 8; ++db) {
      int dg = hh * HD + db * 16 + (lane & 15);
      O[((size_t)bb * SEQ + qg) * HIDDEN + dg] = f2bf(acc[db][r] * inv);
    }
  }
}

extern "C" void kernel_launch(void* const* d_in, const int* in_sizes, int n_in,
                              void* d_out, int out_size, void* d_ws, size_t ws_size,
                              hipStream_t stream) {
  (void)in_sizes; (void)n_in; (void)out_size; (void)ws_size;
  const float* x  = (const float*)d_in[0];
  const float* Wq = (const float*)d_in[1];
  const float* bq = (const float*)d_in[2];
  const float* Wk = (const float*)d_in[3];
  const float* bk = (const float*)d_in[4];
  const float* Wv = (const float*)d_in[5];
  const float* bv = (const float*)d_in[6];
  const float* Wo = (const float*)d_in[7];
  const float* bo = (const float*)d_in[8];
  float* out = (float*)d_out;

  char* ws = (char*)d_ws;
  unsigned short* xbf = (unsigned short*)ws;
  unsigned short* Wbf = (unsigned short*)(ws + 16777216);
  unsigned short* Qbf = (unsigned short*)(ws + 25165824);
  unsigned short* Kbf = (unsigned short*)(ws + 41943040);
  unsigned short* Vbf = (unsigned short*)(ws + 58720256);

  dim3 blk(256);
  dim3 gg(32, 16);
  dim3 ga(32, 32);

  cvt_kernel<<<8192, blk, 0, stream>>>(x, xbf, BATCH * SEQ * HIDDEN);

  cvt_kernel<<<4096, blk, 0, stream>>>(Wq, Wbf, HIDDEN * HIDDEN);
  gemm_nt<0><<<gg, blk, 0, stream>>>(xbf, Wbf, bq, nullptr, Qbf);

  cvt_kernel<<<4096, blk, 0, stream>>>(Wk, Wbf, HIDDEN * HIDDEN);
  gemm_nt<0><<<gg, blk, 0, stream>>>(xbf, Wbf, bk, nullptr, Kbf);

  cvt_kernel<<<4096, blk, 0, stream>>>(Wv, Wbf, HIDDEN * HIDDEN);
  gemm_nt<0><<<gg, blk, 0, stream>>>(xbf, Wbf, bv, nullptr, Vbf);

  attn_kernel<<<ga, blk, 0, stream>>>(Qbf, Kbf, Vbf, xbf);

  cvt_kernel<<<4096, blk, 0, stream>>>(Wo, Wbf, HIDDEN * HIDDEN);
  gemm_nt<1><<<gg, blk, 0, stream>>>(xbf, Wbf, bo, out, nullptr);
}

// Round 3
// 615.086 us; speedup vs baseline: 1.0541x; 1.0541x over previous
//
#include <hip/hip_runtime.h>

#define HIDDEN 2048
#define NH 16
#define HD 128
#define BATCH 2
#define SEQ 2048

typedef __attribute__((ext_vector_type(8))) short short8;
typedef __attribute__((ext_vector_type(4))) float floatx4;

__device__ inline unsigned short f2bf(float f) {
  union { float f; unsigned int u; } x; x.f = f;
  unsigned int r = x.u + 0x7fffu + ((x.u >> 16) & 1u);
  return (unsigned short)(r >> 16);
}
__device__ inline unsigned int pkbf(float a, float b) {
  return (unsigned int)f2bf(a) | ((unsigned int)f2bf(b) << 16);
}

__device__ inline void async_cp16(const void* g, void* l) {
  __builtin_amdgcn_global_load_lds(
      (const __attribute__((address_space(1))) unsigned int*)g,
      (__attribute__((address_space(3))) unsigned int*)l, 16, 0, 0);
}

// ---------------- f32 -> bf16 convert ----------------
__global__ __launch_bounds__(256) void cvt_kernel(const float* __restrict__ in,
                                                  unsigned short* __restrict__ out,
                                                  int n) {
  int i = (blockIdx.x * 256 + threadIdx.x) * 4;
  if (i + 3 < n) {
    float4 v = *reinterpret_cast<const float4*>(in + i);
    ushort4 o;
    o.x = f2bf(v.x); o.y = f2bf(v.y); o.z = f2bf(v.z); o.w = f2bf(v.w);
    *reinterpret_cast<ushort4*>(out + i) = o;
  }
}

// ---------------- NT GEMM, 128x128 tile, BK=32, double-buffered prefetch ----------------
template<int MODE>
__global__ __launch_bounds__(256) void gemm_nt(const unsigned short* __restrict__ A,
                                               const unsigned short* __restrict__ Bw,
                                               const float* __restrict__ bias,
                                               float* __restrict__ outF,
                                               unsigned short* __restrict__ outQ) {
  __shared__ __align__(16) unsigned short As[2][4096];  // [k8][row][8]
  __shared__ __align__(16) unsigned short Bs[2][4096];
  const int t = threadIdx.x;
  const int lane = t & 63;
  const int w = t >> 6;
  const int wr = w >> 1, wc = w & 1;
  const int row0 = blockIdx.x * 128;
  const int col0 = blockIdx.y * 128;

  floatx4 acc[4][4] = {};

  // prologue: stage tile 0
#pragma unroll
  for (int cc = 0; cc < 2; ++cc) {
    int c = t + cc * 256;
    int k8 = c >> 7, r = c & 127;
    async_cp16(A + (size_t)(row0 + r) * 2048 + k8 * 8, &As[0][c * 8]);
    async_cp16(Bw + (size_t)(col0 + r) * 2048 + k8 * 8, &Bs[0][c * 8]);
  }
  __syncthreads();

  int buf = 0;
  for (int kt = 0; kt < 64; ++kt) {
    if (kt < 63) {  // prefetch next tile into other buffer (overlaps compute)
      const int kb = (kt + 1) * 32;
#pragma unroll
      for (int cc = 0; cc < 2; ++cc) {
        int c = t + cc * 256;
        int k8 = c >> 7, r = c & 127;
        async_cp16(A + (size_t)(row0 + r) * 2048 + kb + k8 * 8, &As[buf ^ 1][c * 8]);
        async_cp16(Bw + (size_t)(col0 + r) * 2048 + kb + k8 * 8, &Bs[buf ^ 1][c * 8]);
      }
    }
    short8 af[4], bf[4];
#pragma unroll
    for (int m = 0; m < 4; ++m)
      af[m] = *(const short8*)&As[buf][(lane >> 4) * 1024 + (wr * 64 + m * 16 + (lane & 15)) * 8];
#pragma unroll
    for (int n = 0; n < 4; ++n)
      bf[n] = *(const short8*)&Bs[buf][(lane >> 4) * 1024 + (wc * 64 + n * 16 + (lane & 15)) * 8];
#pragma unroll
    for (int m = 0; m < 4; ++m)
#pragma unroll
      for (int n = 0; n < 4; ++n)
        acc[m][n] = __builtin_amdgcn_mfma_f32_16x16x32_bf16(af[m], bf[n], acc[m][n], 0, 0, 0);
    __syncthreads();  // drains prefetch vmcnt + all waves done with buf
    buf ^= 1;
  }

#pragma unroll
  for (int m = 0; m < 4; ++m) {
#pragma unroll
    for (int n = 0; n < 4; ++n) {
      int gcol = col0 + wc * 64 + n * 16 + (lane & 15);
      float bv = bias[gcol];
#pragma unroll
      for (int r = 0; r < 4; ++r) {
        int grow = row0 + wr * 64 + m * 16 + (lane >> 4) * 4 + r;
        float v = acc[m][n][r] + bv;
        if (MODE == 1) {
          outF[(size_t)grow * 2048 + gcol] = v;
        } else {
          int bb = grow >> 11;
          int ss = grow & 2047;
          int hh = gcol >> 7;
          int dd = gcol & 127;
          outQ[(((size_t)bb * NH + hh) * SEQ + ss) * HD + dd] = f2bf(v);
        }
      }
    }
  }
}

// ---------------- causal flash attention ----------------
// 4 waves x 32 q-rows = 128 q/block, KVBLK=64, swapped QK^T (mfma(K,Q)),
// pi-permuted K staging so P registers are directly the PV A-fragments.
__global__ __launch_bounds__(256) void attn_kernel(const unsigned short* __restrict__ Q,
                                                   const unsigned short* __restrict__ Kg,
                                                   const unsigned short* __restrict__ Vg,
                                                   unsigned short* __restrict__ O) {
  __shared__ __align__(16) unsigned short Ks[16 * 64 * 8];  // [k8][slot][8], 16KB
  __shared__ __align__(16) unsigned short VT[8 * 128 * 8];  // [kvrow][d'][kvlo], 16KB

  const int t = threadIdx.x;
  const int lane = t & 63;
  const int w = t >> 6;
  const int g = lane >> 4;
  const int l15 = lane & 15;

  // work-balance swizzle: pair big causal block with small one
  int gid = blockIdx.x;
  int Wi = (gid < 256) ? gid : 767 - gid;
  const int bx = Wi & 15;
  const int bh = Wi >> 4;
  const int q0 = bx * 128;
  const int bb = bh >> 4;
  const int hh = bh & 15;

  const unsigned short* Qb = Q + (size_t)bh * SEQ * HD;
  const unsigned short* Kb = Kg + (size_t)bh * SEQ * HD;
  const unsigned short* Vb = Vg + (size_t)bh * SEQ * HD;

  const int qw = q0 + w * 32;

  // Q fragments (B-operand): row q = l15, k = kb*32 + g*8 + j
  short8 bq[2][4];
#pragma unroll
  for (int qh = 0; qh < 2; ++qh)
#pragma unroll
    for (int kb = 0; kb < 4; ++kb)
      bq[qh][kb] = *(const short8*)(Qb + (size_t)(qw + qh * 16 + l15) * HD + kb * 32 + g * 8);

  floatx4 acc[2][8] = {};
  float mrun[2] = {-1e30f, -1e30f};
  float lrun[2] = {0.f, 0.f};
  const float scale = 0.08838834764831845f;

  const int ntiles = (q0 >> 6) + 2;
  for (int tk = 0; tk < ntiles; ++tk) {
    const int k0 = tk * 64;
    __syncthreads();
    // K stage: LDS slot s holds global kv = 32*(s>>5) + 8*((s>>2)&3) + 4*((s>>4)&1) + (s&3)
#pragma unroll
    for (int cc = 0; cc < 4; ++cc) {
      int c = t + cc * 256;
      int k8 = c >> 6, s = c & 63;
      int kvs = ((s >> 5) << 5) + (((s >> 2) & 3) << 3) + (((s >> 4) & 1) << 2) + (s & 3);
      async_cp16(Kb + (size_t)(k0 + kvs) * HD + k8 * 8, &Ks[c * 8]);
    }
    // V stage transposed: [kv>>3][d ^ ((d>>3 ^ row)&7)][kv&7], u32 kv-pair writes
#pragma unroll
    for (int cc = 0; cc < 2; ++cc) {
      int c = t + cc * 256;
      int kv = (c >> 4) * 2;
      int d0 = (c & 15) * 8;
      int row = kv >> 3;
      short8 va = *(const short8*)(Vb + (size_t)(k0 + kv) * HD + d0);
      short8 vb = *(const short8*)(Vb + (size_t)(k0 + kv + 1) * HD + d0);
#pragma unroll
      for (int j = 0; j < 8; ++j) {
        int d = d0 + j;
        int dp = d ^ (((d >> 3) ^ row) & 7);
        unsigned int u = (unsigned short)va[j] | ((unsigned int)(unsigned short)vb[j] << 16);
        *(unsigned int*)&VT[(row * 128 + dp) * 8 + (kv & 7)] = u;
      }
    }
    __syncthreads();

    // QK^T swapped: C[kv-slot][q]; lane holds q = l15, kv = 32(kvh>>1)+8g+4(kvh&1)+r
    floatx4 sv[4][2];
#pragma unroll
    for (int kvh = 0; kvh < 4; ++kvh) {
      sv[kvh][0] = (floatx4){0.f, 0.f, 0.f, 0.f};
      sv[kvh][1] = (floatx4){0.f, 0.f, 0.f, 0.f};
#pragma unroll
      for (int kb = 0; kb < 4; ++kb) {
        short8 ak = *(const short8*)&Ks[((kb * 4 + g) * 64 + kvh * 16 + l15) * 8];
        sv[kvh][0] = __builtin_amdgcn_mfma_f32_16x16x32_bf16(ak, bq[0][kb], sv[kvh][0], 0, 0, 0);
        sv[kvh][1] = __builtin_amdgcn_mfma_f32_16x16x32_bf16(ak, bq[1][kb], sv[kvh][1], 0, 0, 0);
      }
    }

    // scale + causal mask
    const bool domask = (k0 + 63 > qw);
#pragma unroll
    for (int kvh = 0; kvh < 4; ++kvh)
#pragma unroll
      for (int qh = 0; qh < 2; ++qh)
#pragma unroll
        for (int r = 0; r < 4; ++r) {
          float s = sv[kvh][qh][r] * scale;
          if (domask) {
            int kvg = k0 + ((kvh >> 1) << 5) + g * 8 + ((kvh & 1) << 2) + r;
            int qg = qw + qh * 16 + l15;
            if (kvg > qg) s = -1e30f;
          }
          sv[kvh][qh][r] = s;
        }

    // online softmax: in-lane 16-value reduce + 2 shfl_xor across groups
#pragma unroll
    for (int qh = 0; qh < 2; ++qh) {
      float mt = sv[0][qh][0];
#pragma unroll
      for (int kvh = 0; kvh < 4; ++kvh)
#pragma unroll
        for (int r = 0; r < 4; ++r)
          mt = fmaxf(mt, sv[kvh][qh][r]);
      mt = fmaxf(mt, __shfl_xor(mt, 16, 64));
      mt = fmaxf(mt, __shfl_xor(mt, 32, 64));
      float mnew = fmaxf(mrun[qh], mt);
      float f = __expf(mrun[qh] - mnew);
      mrun[qh] = mnew;
      float ssum = 0.f;
#pragma unroll
      for (int kvh = 0; kvh < 4; ++kvh)
#pragma unroll
        for (int r = 0; r < 4; ++r) {
          float p = __expf(sv[kvh][qh][r] - mnew);
          sv[kvh][qh][r] = p;
          ssum += p;
        }
      ssum += __shfl_xor(ssum, 16, 64);
      ssum += __shfl_xor(ssum, 32, 64);
      lrun[qh] = lrun[qh] * f + ssum;
      // fetch rescale factor for acc rows q = 4g+r (held by lane l15=4g+r)
      float fr[4];
#pragma unroll
      for (int r = 0; r < 4; ++r)
        fr[r] = __shfl(f, (lane & 48) + 4 * (lane >> 4) + r, 64);
#pragma unroll
      for (int db = 0; db < 8; ++db)
#pragma unroll
        for (int r = 0; r < 4; ++r)
          acc[qh][db][r] *= fr[r];
    }

    // PV: P registers are directly the A-fragments (pi-permutation guarantee)
#pragma unroll
    for (int kh = 0; kh < 2; ++kh) {
      union { short8 s8; unsigned int u[4]; } p0, p1;
      p0.u[0] = pkbf(sv[2 * kh][0][0], sv[2 * kh][0][1]);
      p0.u[1] = pkbf(sv[2 * kh][0][2], sv[2 * kh][0][3]);
      p0.u[2] = pkbf(sv[2 * kh + 1][0][0], sv[2 * kh + 1][0][1]);
      p0.u[3] = pkbf(sv[2 * kh + 1][0][2], sv[2 * kh + 1][0][3]);
      p1.u[0] = pkbf(sv[2 * kh][1][0], sv[2 * kh][1][1]);
      p1.u[1] = pkbf(sv[2 * kh][1][2], sv[2 * kh][1][3]);
      p1.u[2] = pkbf(sv[2 * kh + 1][1][0], sv[2 * kh + 1][1][1]);
      p1.u[3] = pkbf(sv[2 * kh + 1][1][2], sv[2 * kh + 1][1][3]);
      int row = kh * 4 + g;
#pragma unroll
      for (int db = 0; db < 8; ++db) {
        int d = db * 16 + l15;
        int dp = d ^ (((d >> 3) ^ row) & 7);
        short8 bv = *(const short8*)&VT[(row * 128 + dp) * 8];
        acc[0][db] = __builtin_amdgcn_mfma_f32_16x16x32_bf16(p0.s8, bv, acc[0][db], 0, 0, 0);
        acc[1][db] = __builtin_amdgcn_mfma_f32_16x16x32_bf16(p1.s8, bv, acc[1][db], 0, 0, 0);
      }
    }
  }

  // epilogue: normalize, write [B][S][HIDDEN]
#pragma unroll
  for (int qh = 0; qh < 2; ++qh) {
    float inv = 1.0f / lrun[qh];
    float ir[4];
#pragma unroll
    for (int r = 0; r < 4; ++r)
      ir[r] = __shfl(inv, (lane & 48) + 4 * (lane >> 4) + r, 64);
#pragma unroll
    for (int r = 0; r < 4; ++r) {
      int qg = qw + qh * 16 + 4 * g + r;
      size_t base = ((size_t)bb * SEQ + qg) * HIDDEN + hh * HD;
#pragma unroll
      for (int db = 0; db < 8; ++db)
        O[base + db * 16 + l15] = f2bf(acc[qh][db][r] * ir[r]);
    }
  }
}

extern "C" void kernel_launch(void* const* d_in, const int* in_sizes, int n_in,
                              void* d_out, int out_size, void* d_ws, size_t ws_size,
                              hipStream_t stream) {
  (void)in_sizes; (void)n_in; (void)out_size; (void)ws_size;
  const float* x  = (const float*)d_in[0];
  const float* Wq = (const float*)d_in[1];
  const float* bq = (const float*)d_in[2];
  const float* Wk = (const float*)d_in[3];
  const float* bk = (const float*)d_in[4];
  const float* Wv = (const float*)d_in[5];
  const float* bv = (const float*)d_in[6];
  const float* Wo = (const float*)d_in[7];
  const float* bo = (const float*)d_in[8];
  float* out = (float*)d_out;

  char* ws = (char*)d_ws;
  unsigned short* xbf = (unsigned short*)ws;               // 16.78MB; reused as attn output
  unsigned short* Wbf = (unsigned short*)(ws + 16777216);  // 8.39MB, reused per projection
  unsigned short* Qbf = (unsigned short*)(ws + 25165824);
  unsigned short* Kbf = (unsigned short*)(ws + 41943040);
  unsigned short* Vbf = (unsigned short*)(ws + 58720256);  // end 75497472 B

  dim3 blk(256);
  dim3 gg(32, 16);   // M/128 x N/128
  dim3 ga(512);      // (S/128=16) x (B*NH=32), swizzled in-kernel

  cvt_kernel<<<8192, blk, 0, stream>>>(x, xbf, BATCH * SEQ * HIDDEN);

  cvt_kernel<<<4096, blk, 0, stream>>>(Wq, Wbf, HIDDEN * HIDDEN);
  gemm_nt<0><<<gg, blk, 0, stream>>>(xbf, Wbf, bq, nullptr, Qbf);

  cvt_kernel<<<4096, blk, 0, stream>>>(Wk, Wbf, HIDDEN * HIDDEN);
  gemm_nt<0><<<gg, blk, 0, stream>>>(xbf, Wbf, bk, nullptr, Kbf);

  cvt_kernel<<<4096, blk, 0, stream>>>(Wv, Wbf, HIDDEN * HIDDEN);
  gemm_nt<0><<<gg, blk, 0, stream>>>(xbf, Wbf, bv, nullptr, Vbf);

  attn_kernel<<<ga, blk, 0, stream>>>(Qbf, Kbf, Vbf, xbf);

  cvt_kernel<<<4096, blk, 0, stream>>>(Wo, Wbf, HIDDEN * HIDDEN);
  gemm_nt<1><<<gg, blk, 0, stream>>>(xbf, Wbf, bo, out, nullptr);
}

// Round 4
// 600.860 us; speedup vs baseline: 1.0790x; 1.0237x over previous
//
#include <hip/hip_runtime.h>

#define HIDDEN 2048
#define NH 16
#define HD 128
#define BATCH 2
#define SEQ 2048

typedef __attribute__((ext_vector_type(8))) short short8;
typedef __attribute__((ext_vector_type(4))) float floatx4;

__device__ inline unsigned short f2bf(float f) {
  union { float f; unsigned int u; } x; x.f = f;
  unsigned int r = x.u + 0x7fffu + ((x.u >> 16) & 1u);
  return (unsigned short)(r >> 16);
}
__device__ inline unsigned int pkbf(float a, float b) {
  return (unsigned int)f2bf(a) | ((unsigned int)f2bf(b) << 16);
}

__device__ inline void async_cp16(const void* g, void* l) {
  __builtin_amdgcn_global_load_lds(
      (const __attribute__((address_space(1))) unsigned int*)g,
      (__attribute__((address_space(3))) unsigned int*)l, 16, 0, 0);
}

// ---------------- f32 -> bf16 convert ----------------
__global__ __launch_bounds__(256) void cvt_kernel(const float* __restrict__ in,
                                                  unsigned short* __restrict__ out,
                                                  int n) {
  int i = (blockIdx.x * 256 + threadIdx.x) * 4;
  if (i + 3 < n) {
    float4 v = *reinterpret_cast<const float4*>(in + i);
    ushort4 o;
    o.x = f2bf(v.x); o.y = f2bf(v.y); o.z = f2bf(v.z); o.w = f2bf(v.w);
    *reinterpret_cast<ushort4*>(out + i) = o;
  }
}

struct QkvPtrs {
  const unsigned short* W[3];
  const float* b[3];
  unsigned short* oq[3];
  float oscale[3];
};

// ---------------- NT GEMM, 128x128 tile, BK=32, dbuf prefetch, 1-D swizzled grid ----
// MODE 0: bf16 scatter to [B][NH][S][HD] (out selected by wsel); MODE 1: f32 row-major.
template<int MODE>
__global__ __launch_bounds__(256, 4) void gemm_nt(const unsigned short* __restrict__ A,
                                                  QkvPtrs P,
                                                  float* __restrict__ outF) {
  __shared__ __align__(16) unsigned short As[2][4096];  // [k8][row][8]
  __shared__ __align__(16) unsigned short Bs[2][4096];
  const int t = threadIdx.x;
  const int lane = t & 63;
  const int w = t >> 6;
  const int wr = w >> 1, wc = w & 1;

  // XCD-bijective swizzle (nwg % 8 == 0 always here)
  const int nwg = gridDim.x;
  int bid = blockIdx.x;
  int Wi = (bid & 7) * (nwg >> 3) + (bid >> 3);
  const int bx = Wi & 31;   // M-block (M=4096 -> 32)
  const int by = Wi >> 5;   // N-block, possibly fused over 3 weights
  const int wsel = (MODE == 0) ? (by >> 4) : 0;
  const int row0 = bx * 128;
  const int col0 = (by & 15) * 128;

  const unsigned short* Bw = P.W[wsel];
  const float* bias = P.b[wsel];

  floatx4 acc[4][4] = {};

  // prologue: stage tile 0
#pragma unroll
  for (int cc = 0; cc < 2; ++cc) {
    int c = t + cc * 256;
    int k8 = c >> 7, r = c & 127;
    async_cp16(A + (size_t)(row0 + r) * 2048 + k8 * 8, &As[0][c * 8]);
    async_cp16(Bw + (size_t)(col0 + r) * 2048 + k8 * 8, &Bs[0][c * 8]);
  }
  __syncthreads();

  int buf = 0;
  for (int kt = 0; kt < 64; ++kt) {
    if (kt < 63) {  // prefetch next tile (issued before compute; drained at end barrier)
      const int kb = (kt + 1) * 32;
#pragma unroll
      for (int cc = 0; cc < 2; ++cc) {
        int c = t + cc * 256;
        int k8 = c >> 7, r = c & 127;
        async_cp16(A + (size_t)(row0 + r) * 2048 + kb + k8 * 8, &As[buf ^ 1][c * 8]);
        async_cp16(Bw + (size_t)(col0 + r) * 2048 + kb + k8 * 8, &Bs[buf ^ 1][c * 8]);
      }
    }
    short8 af[4], bf[4];
#pragma unroll
    for (int m = 0; m < 4; ++m)
      af[m] = *(const short8*)&As[buf][(lane >> 4) * 1024 + (wr * 64 + m * 16 + (lane & 15)) * 8];
#pragma unroll
    for (int n = 0; n < 4; ++n)
      bf[n] = *(const short8*)&Bs[buf][(lane >> 4) * 1024 + (wc * 64 + n * 16 + (lane & 15)) * 8];
#pragma unroll
    for (int m = 0; m < 4; ++m)
#pragma unroll
      for (int n = 0; n < 4; ++n)
        acc[m][n] = __builtin_amdgcn_mfma_f32_16x16x32_bf16(af[m], bf[n], acc[m][n], 0, 0, 0);
    __syncthreads();
    buf ^= 1;
  }

  const float osc = P.oscale[wsel];
#pragma unroll
  for (int m = 0; m < 4; ++m) {
#pragma unroll
    for (int n = 0; n < 4; ++n) {
      int gcol = col0 + wc * 64 + n * 16 + (lane & 15);
      float bv = bias[gcol];
#pragma unroll
      for (int r = 0; r < 4; ++r) {
        int grow = row0 + wr * 64 + m * 16 + (lane >> 4) * 4 + r;
        float v = acc[m][n][r] + bv;
        if (MODE == 1) {
          outF[(size_t)grow * 2048 + gcol] = v;
        } else {
          int bb = grow >> 11;
          int ss = grow & 2047;
          int hh = gcol >> 7;
          int dd = gcol & 127;
          P.oq[wsel][(((size_t)bb * NH + hh) * SEQ + ss) * HD + dd] = f2bf(v * osc);
        }
      }
    }
  }
}

// ---------------- causal flash attention ----------------
// 4 waves x 32 q = 128 q/block, KVBLK=64, swapped QK^T, pi-permuted K staging,
// depth-1 pipelined K/V staging (double-buffered LDS), defer-max online softmax.
// Q is pre-scaled by 1/sqrt(HD) in the projection epilogue.
__global__ __launch_bounds__(256) void attn_kernel(const unsigned short* __restrict__ Q,
                                                   const unsigned short* __restrict__ Kg,
                                                   const unsigned short* __restrict__ Vg,
                                                   unsigned short* __restrict__ O) {
  __shared__ __align__(16) unsigned short Ks[2][16 * 64 * 8];  // 16KB each
  __shared__ __align__(16) unsigned short VT[2][8 * 128 * 8];  // 16KB each

  const int t = threadIdx.x;
  const int lane = t & 63;
  const int w = t >> 6;
  const int g = lane >> 4;
  const int l15 = lane & 15;

  // work-balance swizzle: pair big causal block with small one
  int gid = blockIdx.x;
  int Wi = (gid < 256) ? gid : 767 - gid;
  const int bx = Wi & 15;
  const int bh = Wi >> 4;
  const int q0 = bx * 128;
  const int bb = bh >> 4;
  const int hh = bh & 15;

  const unsigned short* Qb = Q + (size_t)bh * SEQ * HD;
  const unsigned short* Kb = Kg + (size_t)bh * SEQ * HD;
  const unsigned short* Vb = Vg + (size_t)bh * SEQ * HD;

  const int qw = q0 + w * 32;

  // Q fragments (B-operand): row q = l15, k = kb*32 + g*8 + j
  short8 bq[2][4];
#pragma unroll
  for (int qh = 0; qh < 2; ++qh)
#pragma unroll
    for (int kb = 0; kb < 4; ++kb)
      bq[qh][kb] = *(const short8*)(Qb + (size_t)(qw + qh * 16 + l15) * HD + kb * 32 + g * 8);

  floatx4 acc[2][8] = {};
  float mrun[2] = {-1e30f, -1e30f};
  float lrun[2] = {0.f, 0.f};

  // V prefetch registers (tile t+1), 4 x short8
  short8 vreg[4];
  const int vkv = (t >> 4) * 2;      // kv row pair base for this thread
  const int vd0 = (t & 15) * 8;      // d chunk

  const int ntiles = (q0 >> 6) + 2;

  // ---- prologue: stage tile 0 ----
  {
#pragma unroll
    for (int cc = 0; cc < 4; ++cc) {
      int c = t + cc * 256;
      int k8 = c >> 6, s = c & 63;
      int kvs = ((s >> 5) << 5) + (((s >> 2) & 3) << 3) + (((s >> 4) & 1) << 2) + (s & 3);
      async_cp16(Kb + (size_t)kvs * HD + k8 * 8, &Ks[0][c * 8]);
    }
#pragma unroll
    for (int cc = 0; cc < 2; ++cc) {
      vreg[cc * 2]     = *(const short8*)(Vb + (size_t)(vkv + cc * 32) * HD + vd0);
      vreg[cc * 2 + 1] = *(const short8*)(Vb + (size_t)(vkv + cc * 32 + 1) * HD + vd0);
    }
    // write V(0) into VT[0] (waits its own vmcnt for regs)
#pragma unroll
    for (int cc = 0; cc < 2; ++cc) {
      int kv = vkv + cc * 32;
      int row = kv >> 3;
#pragma unroll
      for (int j = 0; j < 8; ++j) {
        int d = vd0 + j;
        int dp = d ^ (((d >> 3) ^ row) & 7);
        unsigned int u = (unsigned short)vreg[cc * 2][j] |
                         ((unsigned int)(unsigned short)vreg[cc * 2 + 1][j] << 16);
        *(unsigned int*)&VT[0][(row * 128 + dp) * 8 + (kv & 7)] = u;
      }
    }
    __syncthreads();  // drains K(0) gloads + makes VT(0) visible
  }

  for (int tk = 0; tk < ntiles; ++tk) {
    const int buf = tk & 1;
    const int k0 = tk * 64;
    const bool pf = (tk + 1 < ntiles);

    if (pf) {  // issue next tile's loads BEFORE compute (latency hides under compute)
      const int kn = k0 + 64;
#pragma unroll
      for (int cc = 0; cc < 4; ++cc) {
        int c = t + cc * 256;
        int k8 = c >> 6, s = c & 63;
        int kvs = ((s >> 5) << 5) + (((s >> 2) & 3) << 3) + (((s >> 4) & 1) << 2) + (s & 3);
        async_cp16(Kb + (size_t)(kn + kvs) * HD + k8 * 8, &Ks[buf ^ 1][c * 8]);
      }
#pragma unroll
      for (int cc = 0; cc < 2; ++cc) {
        vreg[cc * 2]     = *(const short8*)(Vb + (size_t)(kn + vkv + cc * 32) * HD + vd0);
        vreg[cc * 2 + 1] = *(const short8*)(Vb + (size_t)(kn + vkv + cc * 32 + 1) * HD + vd0);
      }
    }

    // QK^T swapped: lane holds q = l15 (+16*qh), kv = 32(kvh>>1)+8g+4(kvh&1)+r
    floatx4 sv[4][2];
#pragma unroll
    for (int kvh = 0; kvh < 4; ++kvh) {
      sv[kvh][0] = (floatx4){0.f, 0.f, 0.f, 0.f};
      sv[kvh][1] = (floatx4){0.f, 0.f, 0.f, 0.f};
#pragma unroll
      for (int kb = 0; kb < 4; ++kb) {
        short8 ak = *(const short8*)&Ks[buf][((kb * 4 + g) * 64 + kvh * 16 + l15) * 8];
        sv[kvh][0] = __builtin_amdgcn_mfma_f32_16x16x32_bf16(ak, bq[0][kb], sv[kvh][0], 0, 0, 0);
        sv[kvh][1] = __builtin_amdgcn_mfma_f32_16x16x32_bf16(ak, bq[1][kb], sv[kvh][1], 0, 0, 0);
      }
    }

    // causal mask (Q pre-scaled, no scale mult here)
    if (k0 + 63 > qw) {
#pragma unroll
      for (int kvh = 0; kvh < 4; ++kvh)
#pragma unroll
        for (int qh = 0; qh < 2; ++qh)
#pragma unroll
          for (int r = 0; r < 4; ++r) {
            int kvg = k0 + ((kvh >> 1) << 5) + g * 8 + ((kvh & 1) << 2) + r;
            int qg = qw + qh * 16 + l15;
            if (kvg > qg) sv[kvh][qh][r] = -1e30f;
          }
    }

    // online softmax with defer-max (THR=8)
#pragma unroll
    for (int qh = 0; qh < 2; ++qh) {
      float mt = sv[0][qh][0];
#pragma unroll
      for (int kvh = 0; kvh < 4; ++kvh)
#pragma unroll
        for (int r = 0; r < 4; ++r)
          mt = fmaxf(mt, sv[kvh][qh][r]);
      mt = fmaxf(mt, __shfl_xor(mt, 16, 64));
      mt = fmaxf(mt, __shfl_xor(mt, 32, 64));
      if (__any(mt > mrun[qh] + 8.0f)) {  // rescale path (wave-uniform)
        float mnew = fmaxf(mrun[qh], mt);
        float f = __expf(mrun[qh] - mnew);
        mrun[qh] = mnew;
        lrun[qh] *= f;
        float fr[4];
#pragma unroll
        for (int r = 0; r < 4; ++r)
          fr[r] = __shfl(f, (lane & 48) + 4 * g + r, 64);
#pragma unroll
        for (int db = 0; db < 8; ++db)
#pragma unroll
          for (int r = 0; r < 4; ++r)
            acc[qh][db][r] *= fr[r];
      }
      float m = mrun[qh];
      float ssum = 0.f;
#pragma unroll
      for (int kvh = 0; kvh < 4; ++kvh)
#pragma unroll
        for (int r = 0; r < 4; ++r) {
          float p = __expf(sv[kvh][qh][r] - m);
          sv[kvh][qh][r] = p;
          ssum += p;
        }
      ssum += __shfl_xor(ssum, 16, 64);
      ssum += __shfl_xor(ssum, 32, 64);
      lrun[qh] += ssum;
    }

    // PV: P registers are directly the A-fragments (pi-permutation guarantee)
#pragma unroll
    for (int kh = 0; kh < 2; ++kh) {
      union { short8 s8; unsigned int u[4]; } p0, p1;
      p0.u[0] = pkbf(sv[2 * kh][0][0], sv[2 * kh][0][1]);
      p0.u[1] = pkbf(sv[2 * kh][0][2], sv[2 * kh][0][3]);
      p0.u[2] = pkbf(sv[2 * kh + 1][0][0], sv[2 * kh + 1][0][1]);
      p0.u[3] = pkbf(sv[2 * kh + 1][0][2], sv[2 * kh + 1][0][3]);
      p1.u[0] = pkbf(sv[2 * kh][1][0], sv[2 * kh][1][1]);
      p1.u[1] = pkbf(sv[2 * kh][1][2], sv[2 * kh][1][3]);
      p1.u[2] = pkbf(sv[2 * kh + 1][1][0], sv[2 * kh + 1][1][1]);
      p1.u[3] = pkbf(sv[2 * kh + 1][1][2], sv[2 * kh + 1][1][3]);
      int row = kh * 4 + g;
#pragma unroll
      for (int db = 0; db < 8; ++db) {
        int d = db * 16 + l15;
        int dp = d ^ (((d >> 3) ^ row) & 7);
        short8 bv = *(const short8*)&VT[buf][(row * 128 + dp) * 8];
        acc[0][db] = __builtin_amdgcn_mfma_f32_16x16x32_bf16(p0.s8, bv, acc[0][db], 0, 0, 0);
        acc[1][db] = __builtin_amdgcn_mfma_f32_16x16x32_bf16(p1.s8, bv, acc[1][db], 0, 0, 0);
      }
    }

    if (pf) {  // write prefetched V to other buffer, then single barrier
#pragma unroll
      for (int cc = 0; cc < 2; ++cc) {
        int kv = vkv + cc * 32;
        int row = kv >> 3;
#pragma unroll
        for (int j = 0; j < 8; ++j) {
          int d = vd0 + j;
          int dp = d ^ (((d >> 3) ^ row) & 7);
          unsigned int u = (unsigned short)vreg[cc * 2][j] |
                           ((unsigned int)(unsigned short)vreg[cc * 2 + 1][j] << 16);
          *(unsigned int*)&VT[buf ^ 1][(row * 128 + dp) * 8 + (kv & 7)] = u;
        }
      }
      __syncthreads();  // drains K(t+1) gloads (issued ~full compute phase ago) + VT writes
    }
  }

  // epilogue: normalize, write [B][S][HIDDEN]
#pragma unroll
  for (int qh = 0; qh < 2; ++qh) {
    float inv = 1.0f / lrun[qh];
    float ir[4];
#pragma unroll
    for (int r = 0; r < 4; ++r)
      ir[r] = __shfl(inv, (lane & 48) + 4 * g + r, 64);
#pragma unroll
    for (int r = 0; r < 4; ++r) {
      int qg = qw + qh * 16 + 4 * g + r;
      size_t base = ((size_t)bb * SEQ + qg) * HIDDEN + hh * HD;
#pragma unroll
      for (int db = 0; db < 8; ++db)
        O[base + db * 16 + l15] = f2bf(acc[qh][db][r] * ir[r]);
    }
  }
}

extern "C" void kernel_launch(void* const* d_in, const int* in_sizes, int n_in,
                              void* d_out, int out_size, void* d_ws, size_t ws_size,
                              hipStream_t stream) {
  (void)in_sizes; (void)n_in; (void)out_size;
  const float* x  = (const float*)d_in[0];
  const float* Wq = (const float*)d_in[1];
  const float* bq = (const float*)d_in[2];
  const float* Wk = (const float*)d_in[3];
  const float* bk = (const float*)d_in[4];
  const float* Wv = (const float*)d_in[5];
  const float* bv = (const float*)d_in[6];
  const float* Wo = (const float*)d_in[7];
  const float* bo = (const float*)d_in[8];
  float* out = (float*)d_out;

  const float qscale = 0.08838834764831845f;  // 1/sqrt(HD)
  char* ws = (char*)d_ws;
  dim3 blk(256);
  const bool fused = ws_size >= 92274688ull;

  if (fused) {
    unsigned short* xbf = (unsigned short*)ws;                // 16.78MB; reused as attn out
    unsigned short* W0  = (unsigned short*)(ws + 16777216);   // Wq, later Wo
    unsigned short* W1  = (unsigned short*)(ws + 25165824);   // Wk
    unsigned short* W2  = (unsigned short*)(ws + 33554432);   // Wv
    unsigned short* Qbf = (unsigned short*)(ws + 41943040);
    unsigned short* Kbf = (unsigned short*)(ws + 58720256);
    unsigned short* Vbf = (unsigned short*)(ws + 75497472);   // end 92274688

    cvt_kernel<<<8192, blk, 0, stream>>>(x, xbf, BATCH * SEQ * HIDDEN);
    cvt_kernel<<<4096, blk, 0, stream>>>(Wq, W0, HIDDEN * HIDDEN);
    cvt_kernel<<<4096, blk, 0, stream>>>(Wk, W1, HIDDEN * HIDDEN);
    cvt_kernel<<<4096, blk, 0, stream>>>(Wv, W2, HIDDEN * HIDDEN);

    QkvPtrs Pq;
    Pq.W[0] = W0;  Pq.W[1] = W1;  Pq.W[2] = W2;
    Pq.b[0] = bq;  Pq.b[1] = bk;  Pq.b[2] = bv;
    Pq.oq[0] = Qbf; Pq.oq[1] = Kbf; Pq.oq[2] = Vbf;
    Pq.oscale[0] = qscale; Pq.oscale[1] = 1.0f; Pq.oscale[2] = 1.0f;
    gemm_nt<0><<<1536, blk, 0, stream>>>(xbf, Pq, nullptr);

    attn_kernel<<<512, blk, 0, stream>>>(Qbf, Kbf, Vbf, xbf);

    cvt_kernel<<<4096, blk, 0, stream>>>(Wo, W0, HIDDEN * HIDDEN);
    QkvPtrs Po;
    Po.W[0] = W0; Po.W[1] = W0; Po.W[2] = W0;
    Po.b[0] = bo; Po.b[1] = bo; Po.b[2] = bo;
    Po.oq[0] = nullptr; Po.oq[1] = nullptr; Po.oq[2] = nullptr;
    Po.oscale[0] = 1.0f; Po.oscale[1] = 1.0f; Po.oscale[2] = 1.0f;
    gemm_nt<1><<<512, blk, 0, stream>>>(xbf, Po, out);
  } else {
    unsigned short* xbf = (unsigned short*)ws;
    unsigned short* Wbf = (unsigned short*)(ws + 16777216);
    unsigned short* Qbf = (unsigned short*)(ws + 25165824);
    unsigned short* Kbf = (unsigned short*)(ws + 41943040);
    unsigned short* Vbf = (unsigned short*)(ws + 58720256);

    cvt_kernel<<<8192, blk, 0, stream>>>(x, xbf, BATCH * SEQ * HIDDEN);

    const float* biases[3] = {bq, bk, bv};
    const float* wsrc[3] = {Wq, Wk, Wv};
    unsigned short* outs[3] = {Qbf, Kbf, Vbf};
    float oscales[3] = {qscale, 1.0f, 1.0f};
    for (int i = 0; i < 3; ++i) {
      cvt_kernel<<<4096, blk, 0, stream>>>(wsrc[i], Wbf, HIDDEN * HIDDEN);
      QkvPtrs Pp;
      Pp.W[0] = Wbf; Pp.W[1] = Wbf; Pp.W[2] = Wbf;
      Pp.b[0] = biases[i]; Pp.b[1] = biases[i]; Pp.b[2] = biases[i];
      Pp.oq[0] = outs[i]; Pp.oq[1] = outs[i]; Pp.oq[2] = outs[i];
      Pp.oscale[0] = oscales[i]; Pp.oscale[1] = oscales[i]; Pp.oscale[2] = oscales[i];
      gemm_nt<0><<<512, blk, 0, stream>>>(xbf, Pp, nullptr);
    }

    attn_kernel<<<512, blk, 0, stream>>>(Qbf, Kbf, Vbf, xbf);

    cvt_kernel<<<4096, blk, 0, stream>>>(Wo, Wbf, HIDDEN * HIDDEN);
    QkvPtrs Po;
    Po.W[0] = Wbf; Po.W[1] = Wbf; Po.W[2] = Wbf;
    Po.b[0] = bo; Po.b[1] = bo; Po.b[2] = bo;
    Po.oq[0] = nullptr; Po.oq[1] = nullptr; Po.oq[2] = nullptr;
    Po.oscale[0] = 1.0f; Po.oscale[1] = 1.0f; Po.oscale[2] = 1.0f;
    gemm_nt<1><<<512, blk, 0, stream>>>(xbf, Po, out);
  }
}